// Round 8
// baseline (456.754 us; speedup 1.0000x reference)
//
#include <hip/hip_runtime.h>
#include <math.h>

// (S,N,B,T,D) = (8,8,2,2048,1024)
// Grid 8192 = (xcd 8) x (k 1024); XCD owns contiguous btp range; k%4 = s-pair.
// Block: 512 thr = 8 waves. Waves 0-3 -> bt_a (slice w&3), waves 4-7 -> bt_b.
// All 8 V-row chunks register-resident (1 float4 chunk/thread); LDS only for a
// 896 B cross-wave partial exchange. V shared across the 4 sp-blocks via L2.
#define TPB 512

template <int CTRL>
__device__ __forceinline__ float dpp_add(float x) {
    int yi = __builtin_amdgcn_update_dpp(0, __float_as_int(x), CTRL, 0xF, 0xF, true);
    return x + __int_as_float(yi);
}

// 64-lane sum, pure VALU; TOTAL lands in lane 63 (no broadcast - saves a readlane).
__device__ __forceinline__ float wave_sum63(float x) {
    x = dpp_add<0xB1>(x);    // xor 1
    x = dpp_add<0x4E>(x);    // xor 2
    x = dpp_add<0x141>(x);   // row_half_mirror
    x = dpp_add<0x140>(x);   // row_mirror -> 16-lane row sums
    x = dpp_add<0x142>(x);   // row_bcast15
    x = dpp_add<0x143>(x);   // row_bcast31 -> lane63 = total
    return x;
}

__device__ __forceinline__ float dot4(const float4 a, const float4 b) {
    return a.x*b.x + a.y*b.y + a.z*b.z + a.w*b.w;
}

__global__ __launch_bounds__(TPB, 8) void two_phase_attn_kernel(
    const float* __restrict__ q,    // [8][1024]
    const float* __restrict__ V,    // block_reps  [8][2][2048][1024]
    const float* __restrict__ P,    // partial_sums[8][2][2048][1024]
    const float* __restrict__ wgt,  // [1024]
    float* __restrict__ out)        // merged_out | merged_max | merged_lse
{
    constexpr int    N   = 8;
    constexpr int    BT  = 4096;
    constexpr int    D   = 1024;
    constexpr size_t ROW = (size_t)BT * D;
    constexpr size_t OUT_MM  = (size_t)8 * ROW;
    constexpr size_t OUT_LSE = OUT_MM + (size_t)BT * 8;
    constexpr float  SCALE = 0.03125f;
    constexpr float  EPS   = 1e-6f;

    __shared__ float red[8][28];    // per-wave reduced partials (896 B)

    const int tid  = threadIdx.x;
    const int w    = tid >> 6;
    const int lane = tid & 63;

    // XCD-aware decomposition (dispatch round-robins blockIdx % 8 -> XCD)
    const int b   = blockIdx.x;
    const int xcd = b & 7;
    const int k   = b >> 3;               // 0..1023 launch order within XCD
    const int btp = xcd * 256 + (k >> 2); // bt-pair, contiguous per XCD
    const int sp  = k & 3;
    const int s0  = 2 * sp, s1 = s0 + 1;

    const int bt  = 2 * btp + (w >> 2);   // waves 0-3 -> bt_a; 4-7 -> bt_b
    const int d0  = (w & 3) * 256 + lane * 4;
    const size_t btD = (size_t)bt * D;

    // ---- All global loads issued up front (13 independent float4/thread) ----
    float4 v[N];
    #pragma unroll
    for (int n = 0; n < N; ++n)
        v[n] = *(const float4*)(V + (size_t)n * ROW + btD + d0);
    const float4 p0 = *(const float4*)(P + (size_t)s0 * ROW + btD + d0);
    const float4 p1 = *(const float4*)(P + (size_t)s1 * ROW + btD + d0);
    const float4 a0 = *(const float4*)(q + s0 * D + d0);
    const float4 a1 = *(const float4*)(q + s1 * D + d0);
    const float4 wv = *(const float4*)(wgt + d0);
    const float4 qw0 = make_float4(a0.x*wv.x, a0.y*wv.y, a0.z*wv.z, a0.w*wv.w);
    const float4 qw1 = make_float4(a1.x*wv.x, a1.y*wv.y, a1.z*wv.z, a1.w*wv.w);

    // ---- Per-thread partials (28 scalars, 4 FMA each) ----
    // r[0..7]=dot(qw0,V[n]) r[8..15]=dot(qw1,V[n]) r[16..23]=vsq[n]
    // r[24]=ssq(P0) r[25]=ssq(P1) r[26]=dot(qw0,P0) r[27]=dot(qw1,P1)
    float r[28];
    #pragma unroll
    for (int n = 0; n < N; ++n) {
        r[n]      = dot4(qw0, v[n]);
        r[8 + n]  = dot4(qw1, v[n]);
        r[16 + n] = dot4(v[n], v[n]);
    }
    r[24] = dot4(p0, p0);
    r[25] = dot4(p1, p1);
    r[26] = dot4(qw0, p0);
    r[27] = dot4(qw1, p1);

    // ---- Wave reduce (28 independent DPP chains) ----
    #pragma unroll
    for (int i = 0; i < 28; ++i) r[i] = wave_sum63(r[i]);

    // ---- Cross-wave exchange: lane63 packs 7 float4 (static idx), barrier,
    //      lanes 0..27 sum their index across the 4 waves of this bt-group ----
    if (lane == 63) {
        #pragma unroll
        for (int i = 0; i < 7; ++i)
            *(float4*)(&red[w][i*4]) =
                make_float4(r[i*4], r[i*4+1], r[i*4+2], r[i*4+3]);
    }
    __syncthreads();

    const int g = (w >> 2) * 4;           // first wave of this bt-group
    float rv = 0.f;
    if (lane < 28)
        rv = red[g][lane] + red[g+1][lane] + red[g+2][lane] + red[g+3][lane];

    float rs[28];
    #pragma unroll
    for (int i = 0; i < 28; ++i)
        rs[i] = __int_as_float(__builtin_amdgcn_readlane(__float_as_int(rv), i));

    // ---- Phase 1 softmax over n (wave-uniform scalars) ----
    float e0[N], e1[N];
    float m0 = -1e30f, m1 = -1e30f;
    #pragma unroll
    for (int n = 0; n < N; ++n) {
        const float rinv = rsqrtf(rs[16 + n] * (1.0f/1024.0f) + EPS);
        e0[n] = rs[n]     * rinv * SCALE;  m0 = fmaxf(m0, e0[n]);
        e1[n] = rs[8 + n] * rinv * SCALE;  m1 = fmaxf(m1, e1[n]);
    }
    float es0 = 0.f, es1 = 0.f;
    #pragma unroll
    for (int n = 0; n < N; ++n) {
        e0[n] = __expf(e0[n] - m0);  es0 += e0[n];
        e1[n] = __expf(e1[n] - m1);  es1 += e1[n];
    }

    // ---- Phase 2 merge scalars ----
    const float im0 = rs[26] * rsqrtf(rs[24] * (1.0f/1024.0f) + EPS) * SCALE;
    const float im1 = rs[27] * rsqrtf(rs[25] * (1.0f/1024.0f) + EPS) * SCALE;
    const float mm0 = fmaxf(m0, im0),    mm1 = fmaxf(m1, im1);
    const float wi0 = __expf(m0 - mm0),  wi1 = __expf(m1 - mm1);
    const float wa0 = __expf(im0 - mm0), wa1 = __expf(im1 - mm1);
    const float lse0 = __logf(wi0 * es0 + wa0) + mm0;   // exp(inter_lse-inter_max)==es
    const float lse1 = __logf(wi1 * es1 + wa1) + mm1;
    const float nrm0 = wi0 + wa0,         nrm1 = wi1 + wa1;
    const float cA0 = wi0 / (es0 * nrm0), cA1 = wi1 / (es1 * nrm1);
    const float cp0 = wa0 / nrm0,         cp1 = wa1 / nrm1;

    // ---- Phase E: inter_out from register-resident V; merge; store ----
    float4 A0 = make_float4(0.f,0.f,0.f,0.f);
    float4 A1 = make_float4(0.f,0.f,0.f,0.f);
    #pragma unroll
    for (int n = 0; n < N; ++n) {
        const float4 vv = v[n];
        A0.x += e0[n]*vv.x; A0.y += e0[n]*vv.y; A0.z += e0[n]*vv.z; A0.w += e0[n]*vv.w;
        A1.x += e1[n]*vv.x; A1.y += e1[n]*vv.y; A1.z += e1[n]*vv.z; A1.w += e1[n]*vv.w;
    }
    float4 o0, o1;
    o0.x = cA0*A0.x + cp0*p0.x;  o0.y = cA0*A0.y + cp0*p0.y;
    o0.z = cA0*A0.z + cp0*p0.z;  o0.w = cA0*A0.w + cp0*p0.w;
    o1.x = cA1*A1.x + cp1*p1.x;  o1.y = cA1*A1.y + cp1*p1.y;
    o1.z = cA1*A1.z + cp1*p1.z;  o1.w = cA1*A1.w + cp1*p1.w;
    *(float4*)(out + (size_t)s0 * ROW + btD + d0) = o0;
    *(float4*)(out + (size_t)s1 * ROW + btD + d0) = o1;

    if ((w & 3) == 0 && lane == 0) {      // one writer per (bt, s-pair)
        out[OUT_MM  + (size_t)s0 * BT + bt] = mm0;
        out[OUT_MM  + (size_t)s1 * BT + bt] = mm1;
        out[OUT_LSE + (size_t)s0 * BT + bt] = lse0;
        out[OUT_LSE + (size_t)s1 * BT + bt] = lse1;
    }
}

extern "C" void kernel_launch(void* const* d_in, const int* in_sizes, int n_in,
                              void* d_out, int out_size, void* d_ws, size_t ws_size,
                              hipStream_t stream) {
    const float* q   = (const float*)d_in[0];   // pseudo_queries [8,1024]
    const float* V   = (const float*)d_in[1];   // block_reps     [8,2,2048,1024]
    const float* P   = (const float*)d_in[2];   // partial_sums   [8,2,2048,1024]
    const float* wgt = (const float*)d_in[3];   // norm_weight    [1024]
    float* o = (float*)d_out;

    two_phase_attn_kernel<<<8192, TPB, 0, stream>>>(q, V, P, wgt, o);
}